// Round 1
// baseline (1026.049 us; speedup 1.0000x reference)
//
#include <hip/hip_runtime.h>
#include <math.h>

#define B_ 2
#define S_ 2048
#define D_ 512
#define NB_ 64
#define NH_ 6
#define ROWS (B_*S_)           // 4096
#define SCALE 0.044194173824159216f   // 1/sqrt(512)

// ---------------- GEMM NT: C[M,N] = A[M,K] * Bw[N,K]^T (+bias[n]) ----------------
__global__ __launch_bounds__(256) void gemm_nt_bias(
    const float* __restrict__ A, const float* __restrict__ Bw,
    const float* __restrict__ bias, float* __restrict__ C,
    int M, int N, int K)
{
    __shared__ float As[16][68];   // As[k][m]
    __shared__ float Bs[16][68];   // Bs[k][n]
    int tid = threadIdx.x;
    int tx = tid & 15, ty = tid >> 4;
    int m0 = blockIdx.y * 64, n0 = blockIdx.x * 64;
    float acc[4][4] = {};
    for (int k0 = 0; k0 < K; k0 += 16) {
        int r  = tid >> 2;            // 0..63
        int kq = (tid & 3) << 2;      // 0,4,8,12
        float4 a4 = *(const float4*)(A  + (size_t)(m0 + r) * K + k0 + kq);
        As[kq+0][r]=a4.x; As[kq+1][r]=a4.y; As[kq+2][r]=a4.z; As[kq+3][r]=a4.w;
        float4 b4 = *(const float4*)(Bw + (size_t)(n0 + r) * K + k0 + kq);
        Bs[kq+0][r]=b4.x; Bs[kq+1][r]=b4.y; Bs[kq+2][r]=b4.z; Bs[kq+3][r]=b4.w;
        __syncthreads();
        #pragma unroll
        for (int k = 0; k < 16; ++k) {
            float a[4], b[4];
            *(float4*)a = *(const float4*)&As[k][ty << 2];
            *(float4*)b = *(const float4*)&Bs[k][tx << 2];
            #pragma unroll
            for (int i = 0; i < 4; ++i)
                #pragma unroll
                for (int j = 0; j < 4; ++j)
                    acc[i][j] = fmaf(a[i], b[j], acc[i][j]);
        }
        __syncthreads();
    }
    #pragma unroll
    for (int i = 0; i < 4; ++i) {
        int m = m0 + (ty << 2) + i;
        #pragma unroll
        for (int j = 0; j < 4; ++j) {
            int n = n0 + (tx << 2) + j;
            float cv = acc[i][j];
            if (bias) cv += bias[n];
            C[(size_t)m * N + n] = cv;
        }
    }
}

// ---------------- GEMM NN + epilogue: C = A[M,K]*Bm[K,N] + (sumVall - sumVb[bucket[m]])/S ----
__global__ __launch_bounds__(256) void gemm_nn_ep(
    const float* __restrict__ A, const float* __restrict__ Bm,
    float* __restrict__ C, int M, int N, int K,
    const float* __restrict__ sumVall, const float* __restrict__ sumVb,
    const int* __restrict__ bucketRow)
{
    __shared__ float As[16][68];   // As[k][m]
    __shared__ float Bs[16][68];   // Bs[k][n]
    int tid = threadIdx.x;
    int tx = tid & 15, ty = tid >> 4;
    int m0 = blockIdx.y * 64, n0 = blockIdx.x * 64;
    float acc[4][4] = {};
    for (int k0 = 0; k0 < K; k0 += 16) {
        int r  = tid >> 2;
        int kq = (tid & 3) << 2;
        float4 a4 = *(const float4*)(A + (size_t)(m0 + r) * K + k0 + kq);
        As[kq+0][r]=a4.x; As[kq+1][r]=a4.y; As[kq+2][r]=a4.z; As[kq+3][r]=a4.w;
        int rb = tid >> 4;            // 0..15
        int nq = (tid & 15) << 2;     // 0..60
        float4 b4 = *(const float4*)(Bm + (size_t)(k0 + rb) * N + n0 + nq);
        *(float4*)&Bs[rb][nq] = b4;
        __syncthreads();
        #pragma unroll
        for (int k = 0; k < 16; ++k) {
            float a[4], b[4];
            *(float4*)a = *(const float4*)&As[k][ty << 2];
            *(float4*)b = *(const float4*)&Bs[k][tx << 2];
            #pragma unroll
            for (int i = 0; i < 4; ++i)
                #pragma unroll
                for (int j = 0; j < 4; ++j)
                    acc[i][j] = fmaf(a[i], b[j], acc[i][j]);
        }
        __syncthreads();
    }
    const float invS = 1.0f / (float)S_;
    #pragma unroll
    for (int i = 0; i < 4; ++i) {
        int m = m0 + (ty << 2) + i;
        int bm = bucketRow[m];
        #pragma unroll
        for (int j = 0; j < 4; ++j) {
            int n = n0 + (tx << 2) + j;
            float cv = acc[i][j] + (sumVall[n] - sumVb[(size_t)bm * D_ + n]) * invS;
            C[(size_t)m * N + n] = cv;
        }
    }
}

// ---------------- buckets + M (row max proxy = ||q||^2 * scale) ----------------
__global__ __launch_bounds__(64) void bucket_kernel(
    const float* __restrict__ q, const float* __restrict__ H,
    int* __restrict__ bucket, float* __restrict__ Mrow)
{
    int row = blockIdx.x;
    int lane = threadIdx.x;
    const float* qr = q + (size_t)row * D_;
    float proj[NH_] = {};
    float nrm = 0.f;
    for (int d = lane; d < D_; d += 64) {
        float qv = qr[d];
        nrm = fmaf(qv, qv, nrm);
        #pragma unroll
        for (int n = 0; n < NH_; ++n)
            proj[n] = fmaf(qv, H[d * NH_ + n], proj[n]);
    }
    #pragma unroll
    for (int off = 32; off; off >>= 1) {
        nrm += __shfl_down(nrm, off);
        #pragma unroll
        for (int n = 0; n < NH_; ++n) proj[n] += __shfl_down(proj[n], off);
    }
    if (lane == 0) {
        int bk = 0;
        #pragma unroll
        for (int n = 0; n < NH_; ++n) {
            float p = proj[n] + H[D_ * NH_ + n];   // +1 feature * bias row
            if (p >= 0.f) bk |= (1 << n);
        }
        bucket[row] = bk;
        Mrow[row] = nrm * SCALE;
    }
}

// ---------------- per-(b,j) counts + sumV; j==NB -> sum over all ----------------
__global__ __launch_bounds__(256) void sumv_kernel(
    const float* __restrict__ v, const int* __restrict__ bucket,
    float* __restrict__ sumVb, float* __restrict__ sumVall, int* __restrict__ cnt)
{
    int j = blockIdx.x;          // 0..NB_, NB_ == all
    int b = blockIdx.y;
    int tid = threadIdx.x;
    const float* vb = v + (size_t)b * S_ * D_;
    const int* bk = bucket + b * S_;
    float s0 = 0.f, s1 = 0.f;
    int c = 0;
    for (int s = 0; s < S_; ++s) {
        if (j == NB_ || bk[s] == j) {
            s0 += vb[(size_t)s * D_ + tid];
            s1 += vb[(size_t)s * D_ + tid + 256];
            ++c;
        }
    }
    if (j == NB_) {
        sumVall[b * D_ + tid] = s0;
        sumVall[b * D_ + tid + 256] = s1;
    } else {
        sumVb[((size_t)b * NB_ + j) * D_ + tid] = s0;
        sumVb[((size_t)b * NB_ + j) * D_ + tid + 256] = s1;
        if (tid == 0) cnt[b * NB_ + j] = c;
    }
}

// ---------------- in-place E = exp(A*scale - M[row]) ----------------
__global__ void exp_kernel(float* __restrict__ E, const float* __restrict__ Mrow)
{
    size_t total = (size_t)B_ * S_ * S_ / 4;
    for (size_t i = (size_t)blockIdx.x * blockDim.x + threadIdx.x; i < total;
         i += (size_t)gridDim.x * blockDim.x) {
        size_t row = i / (S_ / 4);
        float m = Mrow[row];
        float4 a = *(float4*)(E + i * 4);
        a.x = __expf(a.x * SCALE - m);
        a.y = __expf(a.y * SCALE - m);
        a.z = __expf(a.z * SCALE - m);
        a.w = __expf(a.w * SCALE - m);
        *(float4*)(E + i * 4) = a;
    }
}

// ---------------- per-row bucket-segmented column sums Z[row][64] ----------------
__global__ __launch_bounds__(256) void z_kernel(
    const float* __restrict__ E, const int* __restrict__ bucket,
    float* __restrict__ Z)
{
    int row = blockIdx.x;        // global row 0..4095
    int b = row / S_;
    __shared__ float zl[NB_];
    int tid = threadIdx.x;
    if (tid < NB_) zl[tid] = 0.f;
    __syncthreads();
    const float* Er = E + (size_t)row * S_;
    const int* bk = bucket + b * S_;
    for (int t = tid; t < S_; t += 256)
        atomicAdd(&zl[bk[t]], Er[t]);
    __syncthreads();
    if (tid < NB_) Z[(size_t)row * NB_ + tid] = zl[tid];
}

// ---------------- w_j[row] = 1/(Ztot - Z_j + c_j*exp(-M)), w_{b_s}=0; W=sum ----------------
__global__ __launch_bounds__(64) void w_kernel(
    const float* __restrict__ Z, const int* __restrict__ cnt,
    const int* __restrict__ bucket, const float* __restrict__ Mrow,
    float* __restrict__ w, float* __restrict__ Wsum)
{
    int row = blockIdx.x;
    int j = threadIdx.x;         // 0..63
    int b = row / S_;
    float zj = Z[(size_t)row * NB_ + j];
    float ztot = zj;
    #pragma unroll
    for (int off = 32; off; off >>= 1) ztot += __shfl_xor(ztot, off);
    int bs = bucket[row];
    float em = __expf(-Mrow[row]);
    float wj = 0.f;
    if (j != bs) wj = 1.0f / (ztot - zj + (float)cnt[b * NB_ + j] * em);
    float Wt = wj;
    #pragma unroll
    for (int off = 32; off; off >>= 1) Wt += __shfl_xor(Wt, off);
    w[(size_t)row * NB_ + j] = wj;
    if (j == 0) Wsum[row] = Wt;
}

// ---------------- E' = E * (W[row] - w[row][bucket[t]]) ----------------
__global__ void gamma_kernel(
    float* __restrict__ E, const int* __restrict__ bucket,
    const float* __restrict__ w, const float* __restrict__ Wsum)
{
    size_t total = (size_t)B_ * S_ * S_ / 4;
    for (size_t i = (size_t)blockIdx.x * blockDim.x + threadIdx.x; i < total;
         i += (size_t)gridDim.x * blockDim.x) {
        size_t row = i / (S_ / 4);
        int b = (int)(row / S_);
        int t0 = (int)(i % (S_ / 4)) * 4;
        float Wt = Wsum[row];
        const float* wr = w + row * NB_;
        int4 bj = *(const int4*)(bucket + (size_t)b * S_ + t0);
        float4 a = *(float4*)(E + i * 4);
        a.x *= (Wt - wr[bj.x]);
        a.y *= (Wt - wr[bj.y]);
        a.z *= (Wt - wr[bj.z]);
        a.w *= (Wt - wr[bj.w]);
        *(float4*)(E + i * 4) = a;
    }
}

extern "C" void kernel_launch(void* const* d_in, const int* in_sizes, int n_in,
                              void* d_out, int out_size, void* d_ws, size_t ws_size,
                              hipStream_t stream) {
    (void)in_sizes; (void)n_in; (void)out_size; (void)ws_size;
    const float* x  = (const float*)d_in[0];
    const float* Wq = (const float*)d_in[1];
    const float* bq = (const float*)d_in[2];
    const float* Wv = (const float*)d_in[3];
    const float* bv = (const float*)d_in[4];
    const float* H  = (const float*)d_in[5];
    float* out = (float*)d_out;

    float* q       = (float*)d_ws;                 // 4096*512
    float* v       = q + (size_t)ROWS * D_;        // 4096*512
    float* E       = v + (size_t)ROWS * D_;        // 2*2048*2048
    float* Z       = E + (size_t)B_ * S_ * S_;     // 4096*64
    float* w       = Z + (size_t)ROWS * NB_;       // 4096*64
    float* Wsum    = w + (size_t)ROWS * NB_;       // 4096
    float* Mrow    = Wsum + ROWS;                  // 4096
    float* sumVb   = Mrow + ROWS;                  // 2*64*512
    float* sumVall = sumVb + B_ * NB_ * D_;        // 2*512
    int*   bucket  = (int*)(sumVall + B_ * D_);    // 4096
    int*   cnt     = bucket + ROWS;                // 128

    // 1. q = x Wq^T + bq ; v = x Wv^T + bv
    gemm_nt_bias<<<dim3(D_ / 64, ROWS / 64), 256, 0, stream>>>(x, Wq, bq, q, ROWS, D_, D_);
    gemm_nt_bias<<<dim3(D_ / 64, ROWS / 64), 256, 0, stream>>>(x, Wv, bv, v, ROWS, D_, D_);
    // 2. buckets + M
    bucket_kernel<<<ROWS, 64, 0, stream>>>(q, H, bucket, Mrow);
    // 3. per-bucket counts + sumV (+ sumVall at j==NB_)
    sumv_kernel<<<dim3(NB_ + 1, B_), 256, 0, stream>>>(v, bucket, sumVb, sumVall, cnt);
    // 4. A = q q^T per batch
    for (int b = 0; b < B_; ++b)
        gemm_nt_bias<<<dim3(S_ / 64, S_ / 64), 256, 0, stream>>>(
            q + (size_t)b * S_ * D_, q + (size_t)b * S_ * D_, nullptr,
            E + (size_t)b * S_ * S_, S_, S_, D_);
    // 5. E = exp(A*scale - M)
    exp_kernel<<<2048, 256, 0, stream>>>(E, Mrow);
    // 6. Z_j per row
    z_kernel<<<ROWS, 256, 0, stream>>>(E, bucket, Z);
    // 7. w, W per row
    w_kernel<<<ROWS, 64, 0, stream>>>(Z, cnt, bucket, Mrow, w, Wsum);
    // 8. E' = E * Gamma
    gamma_kernel<<<2048, 256, 0, stream>>>(E, bucket, w, Wsum);
    // 9. out = E' v + rowterm
    for (int b = 0; b < B_; ++b)
        gemm_nn_ep<<<dim3(D_ / 64, S_ / 64), 256, 0, stream>>>(
            E + (size_t)b * S_ * S_, v + (size_t)b * S_ * D_,
            out + (size_t)b * S_ * D_, S_, D_, S_,
            sumVall + b * D_, sumVb + (size_t)b * NB_ * D_, bucket + b * S_);
}

// Round 2
// 542.176 us; speedup vs baseline: 1.8925x; 1.8925x over previous
//
#include <hip/hip_runtime.h>
#include <math.h>

#define B_ 2
#define S_ 2048
#define D_ 512
#define NB_ 64
#define NH_ 6
#define ROWS (B_*S_)           // 4096
#define SCALE 0.044194173824159216f   // 1/sqrt(512)

// ---------------- GEMM NT: C[M,N] = A[M,K] * Bw[N,K]^T (+bias[n]) ----------------
__global__ __launch_bounds__(256) void gemm_nt_bias(
    const float* __restrict__ A, const float* __restrict__ Bw,
    const float* __restrict__ bias, float* __restrict__ C,
    int M, int N, int K)
{
    __shared__ float As[16][68];   // As[k][m]
    __shared__ float Bs[16][68];   // Bs[k][n]
    int tid = threadIdx.x;
    int tx = tid & 15, ty = tid >> 4;
    int m0 = blockIdx.y * 64, n0 = blockIdx.x * 64;
    float acc[4][4] = {};
    for (int k0 = 0; k0 < K; k0 += 16) {
        int r  = tid >> 2;            // 0..63
        int kq = (tid & 3) << 2;      // 0,4,8,12
        float4 a4 = *(const float4*)(A  + (size_t)(m0 + r) * K + k0 + kq);
        As[kq+0][r]=a4.x; As[kq+1][r]=a4.y; As[kq+2][r]=a4.z; As[kq+3][r]=a4.w;
        float4 b4 = *(const float4*)(Bw + (size_t)(n0 + r) * K + k0 + kq);
        Bs[kq+0][r]=b4.x; Bs[kq+1][r]=b4.y; Bs[kq+2][r]=b4.z; Bs[kq+3][r]=b4.w;
        __syncthreads();
        #pragma unroll
        for (int k = 0; k < 16; ++k) {
            float a[4], b[4];
            *(float4*)a = *(const float4*)&As[k][ty << 2];
            *(float4*)b = *(const float4*)&Bs[k][tx << 2];
            #pragma unroll
            for (int i = 0; i < 4; ++i)
                #pragma unroll
                for (int j = 0; j < 4; ++j)
                    acc[i][j] = fmaf(a[i], b[j], acc[i][j]);
        }
        __syncthreads();
    }
    #pragma unroll
    for (int i = 0; i < 4; ++i) {
        int m = m0 + (ty << 2) + i;
        #pragma unroll
        for (int j = 0; j < 4; ++j) {
            int n = n0 + (tx << 2) + j;
            float cv = acc[i][j];
            if (bias) cv += bias[n];
            C[(size_t)m * N + n] = cv;
        }
    }
}

// ---------------- GEMM NN + epilogue: C = A[M,K]*Bm[K,N] + (sumVall - sumVb[bucket[m]])/S ----
__global__ __launch_bounds__(256) void gemm_nn_ep(
    const float* __restrict__ A, const float* __restrict__ Bm,
    float* __restrict__ C, int M, int N, int K,
    const float* __restrict__ sumVall, const float* __restrict__ sumVb,
    const int* __restrict__ bucketRow)
{
    __shared__ float As[16][68];   // As[k][m]
    __shared__ float Bs[16][68];   // Bs[k][n]
    int tid = threadIdx.x;
    int tx = tid & 15, ty = tid >> 4;
    int m0 = blockIdx.y * 64, n0 = blockIdx.x * 64;
    float acc[4][4] = {};
    for (int k0 = 0; k0 < K; k0 += 16) {
        int r  = tid >> 2;
        int kq = (tid & 3) << 2;
        float4 a4 = *(const float4*)(A + (size_t)(m0 + r) * K + k0 + kq);
        As[kq+0][r]=a4.x; As[kq+1][r]=a4.y; As[kq+2][r]=a4.z; As[kq+3][r]=a4.w;
        int rb = tid >> 4;            // 0..15
        int nq = (tid & 15) << 2;     // 0..60
        float4 b4 = *(const float4*)(Bm + (size_t)(k0 + rb) * N + n0 + nq);
        *(float4*)&Bs[rb][nq] = b4;
        __syncthreads();
        #pragma unroll
        for (int k = 0; k < 16; ++k) {
            float a[4], b[4];
            *(float4*)a = *(const float4*)&As[k][ty << 2];
            *(float4*)b = *(const float4*)&Bs[k][tx << 2];
            #pragma unroll
            for (int i = 0; i < 4; ++i)
                #pragma unroll
                for (int j = 0; j < 4; ++j)
                    acc[i][j] = fmaf(a[i], b[j], acc[i][j]);
        }
        __syncthreads();
    }
    const float invS = 1.0f / (float)S_;
    #pragma unroll
    for (int i = 0; i < 4; ++i) {
        int m = m0 + (ty << 2) + i;
        int bm = bucketRow[m];
        #pragma unroll
        for (int j = 0; j < 4; ++j) {
            int n = n0 + (tx << 2) + j;
            float cv = acc[i][j] + (sumVall[n] - sumVb[(size_t)bm * D_ + n]) * invS;
            C[(size_t)m * N + n] = cv;
        }
    }
}

// ---------------- buckets + M (row max proxy = ||q||^2 * scale) ----------------
__global__ __launch_bounds__(64) void bucket_kernel(
    const float* __restrict__ q, const float* __restrict__ H,
    int* __restrict__ bucket, float* __restrict__ Mrow)
{
    int row = blockIdx.x;
    int lane = threadIdx.x;
    const float* qr = q + (size_t)row * D_;
    float proj[NH_] = {};
    float nrm = 0.f;
    for (int d = lane; d < D_; d += 64) {
        float qv = qr[d];
        nrm = fmaf(qv, qv, nrm);
        #pragma unroll
        for (int n = 0; n < NH_; ++n)
            proj[n] = fmaf(qv, H[d * NH_ + n], proj[n]);
    }
    #pragma unroll
    for (int off = 32; off; off >>= 1) {
        nrm += __shfl_down(nrm, off);
        #pragma unroll
        for (int n = 0; n < NH_; ++n) proj[n] += __shfl_down(proj[n], off);
    }
    if (lane == 0) {
        int bk = 0;
        #pragma unroll
        for (int n = 0; n < NH_; ++n) {
            float p = proj[n] + H[D_ * NH_ + n];   // +1 feature * bias row
            if (p >= 0.f) bk |= (1 << n);
        }
        bucket[row] = bk;
        Mrow[row] = nrm * SCALE;
    }
}

// ---------------- zero counters ----------------
__global__ void zero_cnt(int* __restrict__ cnt) { cnt[threadIdx.x] = 0; }

// ---------------- histogram: per-(b,j) count + row index lists ----------------
__global__ __launch_bounds__(256) void hist_kernel(
    const int* __restrict__ bucket, int* __restrict__ cnt, int* __restrict__ idxl)
{
    int r = blockIdx.x * 256 + threadIdx.x;   // 0..ROWS-1
    int b = r / S_;
    int s = r - b * S_;
    int j = bucket[r];
    int pos = atomicAdd(&cnt[b * NB_ + j], 1);
    idxl[((size_t)(b * NB_ + j)) * S_ + pos] = s;
}

// ---------------- sumVb[b,j,:] = sum of v rows in bucket j ----------------
__global__ __launch_bounds__(256) void sumv2_kernel(
    const float* __restrict__ v, const int* __restrict__ cnt,
    const int* __restrict__ idxl, float* __restrict__ sumVb)
{
    int j = blockIdx.x, b = blockIdx.y;
    int d = blockIdx.z * 256 + threadIdx.x;
    int n = cnt[b * NB_ + j];
    const int* lst = idxl + ((size_t)(b * NB_ + j)) * S_;
    const float* vb = v + (size_t)b * S_ * D_;
    float acc = 0.f;
    for (int k = 0; k < n; ++k)
        acc += vb[(size_t)lst[k] * D_ + d];
    sumVb[((size_t)b * NB_ + j) * D_ + d] = acc;
}

// ---------------- sumVall[b,:] = sum_j sumVb[b,j,:] ----------------
__global__ __launch_bounds__(256) void sumvall_kernel(
    const float* __restrict__ sumVb, float* __restrict__ sumVall)
{
    int b = blockIdx.y;
    int d = blockIdx.x * 256 + threadIdx.x;
    float acc = 0.f;
    for (int j = 0; j < NB_; ++j)
        acc += sumVb[((size_t)b * NB_ + j) * D_ + d];
    sumVall[b * D_ + d] = acc;
}

// ---------------- fused: E = exp(A*scale - M[row]); Z[row][j] = sum over bucket j ----------------
__global__ __launch_bounds__(256) void expz_kernel(
    float* __restrict__ E, const int* __restrict__ bucket,
    const float* __restrict__ Mrow, float* __restrict__ Z)
{
    int row = blockIdx.x;        // global row 0..ROWS-1
    int b = row / S_;
    __shared__ float zl[NB_];
    int tid = threadIdx.x;
    if (tid < NB_) zl[tid] = 0.f;
    __syncthreads();
    float m = Mrow[row];
    float* Er = E + (size_t)row * S_;
    const int* bk = bucket + b * S_;
    for (int t0 = tid * 4; t0 < S_; t0 += 1024) {
        float4 a = *(float4*)(Er + t0);
        a.x = __expf(a.x * SCALE - m);
        a.y = __expf(a.y * SCALE - m);
        a.z = __expf(a.z * SCALE - m);
        a.w = __expf(a.w * SCALE - m);
        *(float4*)(Er + t0) = a;
        int4 bj = *(const int4*)(bk + t0);
        atomicAdd(&zl[bj.x], a.x);
        atomicAdd(&zl[bj.y], a.y);
        atomicAdd(&zl[bj.z], a.z);
        atomicAdd(&zl[bj.w], a.w);
    }
    __syncthreads();
    if (tid < NB_) Z[(size_t)row * NB_ + tid] = zl[tid];
}

// ---------------- w_j[row] = 1/(Ztot - Z_j + c_j*exp(-M)), w_{b_s}=0; W=sum ----------------
__global__ __launch_bounds__(64) void w_kernel(
    const float* __restrict__ Z, const int* __restrict__ cnt,
    const int* __restrict__ bucket, const float* __restrict__ Mrow,
    float* __restrict__ w, float* __restrict__ Wsum)
{
    int row = blockIdx.x;
    int j = threadIdx.x;         // 0..63
    int b = row / S_;
    float zj = Z[(size_t)row * NB_ + j];
    float ztot = zj;
    #pragma unroll
    for (int off = 32; off; off >>= 1) ztot += __shfl_xor(ztot, off);
    int bs = bucket[row];
    float em = __expf(-Mrow[row]);
    float wj = 0.f;
    if (j != bs) wj = 1.0f / (ztot - zj + (float)cnt[b * NB_ + j] * em);
    float Wt = wj;
    #pragma unroll
    for (int off = 32; off; off >>= 1) Wt += __shfl_xor(Wt, off);
    w[(size_t)row * NB_ + j] = wj;
    if (j == 0) Wsum[row] = Wt;
}

// ---------------- E' = E * (W[row] - w[row][bucket[t]]) ----------------
__global__ void gamma_kernel(
    float* __restrict__ E, const int* __restrict__ bucket,
    const float* __restrict__ w, const float* __restrict__ Wsum)
{
    size_t total = (size_t)B_ * S_ * S_ / 4;
    for (size_t i = (size_t)blockIdx.x * blockDim.x + threadIdx.x; i < total;
         i += (size_t)gridDim.x * blockDim.x) {
        size_t row = i / (S_ / 4);
        int b = (int)(row / S_);
        int t0 = (int)(i % (S_ / 4)) * 4;
        float Wt = Wsum[row];
        const float* wr = w + row * NB_;
        int4 bj = *(const int4*)(bucket + (size_t)b * S_ + t0);
        float4 a = *(float4*)(E + i * 4);
        a.x *= (Wt - wr[bj.x]);
        a.y *= (Wt - wr[bj.y]);
        a.z *= (Wt - wr[bj.z]);
        a.w *= (Wt - wr[bj.w]);
        *(float4*)(E + i * 4) = a;
    }
}

extern "C" void kernel_launch(void* const* d_in, const int* in_sizes, int n_in,
                              void* d_out, int out_size, void* d_ws, size_t ws_size,
                              hipStream_t stream) {
    (void)in_sizes; (void)n_in; (void)out_size; (void)ws_size;
    const float* x  = (const float*)d_in[0];
    const float* Wq = (const float*)d_in[1];
    const float* bq = (const float*)d_in[2];
    const float* Wv = (const float*)d_in[3];
    const float* bv = (const float*)d_in[4];
    const float* H  = (const float*)d_in[5];
    float* out = (float*)d_out;

    float* q       = (float*)d_ws;                 // 4096*512
    float* v       = q + (size_t)ROWS * D_;        // 4096*512
    float* E       = v + (size_t)ROWS * D_;        // 2*2048*2048
    float* Z       = E + (size_t)B_ * S_ * S_;     // 4096*64
    float* w       = Z + (size_t)ROWS * NB_;       // 4096*64
    float* Wsum    = w + (size_t)ROWS * NB_;       // 4096
    float* Mrow    = Wsum + ROWS;                  // 4096
    float* sumVb   = Mrow + ROWS;                  // 2*64*512
    float* sumVall = sumVb + B_ * NB_ * D_;        // 2*512
    int*   bucket  = (int*)(sumVall + B_ * D_);    // 4096
    int*   cnt     = bucket + ROWS;                // 128
    int*   idxl    = cnt + B_ * NB_;               // 2*64*2048 = 256K ints

    // 1. q = x Wq^T + bq ; v = x Wv^T + bv
    gemm_nt_bias<<<dim3(D_ / 64, ROWS / 64), 256, 0, stream>>>(x, Wq, bq, q, ROWS, D_, D_);
    gemm_nt_bias<<<dim3(D_ / 64, ROWS / 64), 256, 0, stream>>>(x, Wv, bv, v, ROWS, D_, D_);
    // 2. buckets + M
    bucket_kernel<<<ROWS, 64, 0, stream>>>(q, H, bucket, Mrow);
    // 3. histogram + per-bucket sumV + total sumV
    zero_cnt<<<1, B_ * NB_, 0, stream>>>(cnt);
    hist_kernel<<<ROWS / 256, 256, 0, stream>>>(bucket, cnt, idxl);
    sumv2_kernel<<<dim3(NB_, B_, D_ / 256), 256, 0, stream>>>(v, cnt, idxl, sumVb);
    sumvall_kernel<<<dim3(D_ / 256, B_), 256, 0, stream>>>(sumVb, sumVall);
    // 4. A = q q^T per batch
    for (int b = 0; b < B_; ++b)
        gemm_nt_bias<<<dim3(S_ / 64, S_ / 64), 256, 0, stream>>>(
            q + (size_t)b * S_ * D_, q + (size_t)b * S_ * D_, nullptr,
            E + (size_t)b * S_ * S_, S_, S_, D_);
    // 5+6. E = exp(A*scale - M), Z_j per row (fused)
    expz_kernel<<<ROWS, 256, 0, stream>>>(E, bucket, Mrow, Z);
    // 7. w, W per row
    w_kernel<<<ROWS, 64, 0, stream>>>(Z, cnt, bucket, Mrow, w, Wsum);
    // 8. E' = E * Gamma
    gamma_kernel<<<2048, 256, 0, stream>>>(E, bucket, w, Wsum);
    // 9. out = E' v + rowterm
    for (int b = 0; b < B_; ++b)
        gemm_nn_ep<<<dim3(D_ / 64, S_ / 64), 256, 0, stream>>>(
            E + (size_t)b * S_ * S_, v + (size_t)b * S_ * D_,
            out + (size_t)b * S_ * D_, S_, D_, S_,
            sumVall + b * D_, sumVb + (size_t)b * NB_ * D_, bucket + b * S_);
}

// Round 3
// 190.233 us; speedup vs baseline: 5.3936x; 2.8501x over previous
//
#include <hip/hip_runtime.h>
#include <math.h>

#define B_ 2
#define S_ 2048
#define D_ 512
#define NB_ 64
#define NH_ 6
#define ROWS (B_*S_)           // 4096
#define SCALE 0.044194173824159216f   // 1/sqrt(512)

typedef float f32x4 __attribute__((ext_vector_type(4)));
typedef __bf16 bf16v8 __attribute__((ext_vector_type(8)));
typedef short s16x8 __attribute__((ext_vector_type(8)));

__device__ __forceinline__ float b2f(unsigned short u) {
    unsigned int v = (unsigned int)u << 16;
    float f; __builtin_memcpy(&f, &v, 4); return f;
}
__device__ __forceinline__ unsigned short f2b(float f) {
    unsigned int v; __builtin_memcpy(&v, &f, 4);
    v += 0x7fffu + ((v >> 16) & 1u);      // RNE
    return (unsigned short)(v >> 16);
}

#define GLOAD16(g, l) __builtin_amdgcn_global_load_lds( \
    (const __attribute__((address_space(1))) unsigned int*)(g), \
    (__attribute__((address_space(3))) unsigned int*)(uintptr_t)(l), 16, 0, 0)

// stage [128 rows][64 cols] bf16 tile from src(row r0.., col k0..), row-stride ld.
// LDS linear 128B/row; content swizzle: LDS[r][c16] = G[r][c16 ^ (r&7)]
__device__ __forceinline__ void stage_tile(
    const unsigned short* __restrict__ src, int r0, int k0, int ld,
    unsigned short* lds, int w, int l)
{
    #pragma unroll
    for (int j = 0; j < 4; ++j) {
        int chunk = w * 4 + j;                 // 0..15, 1KB each
        int r = chunk * 8 + (l >> 3);
        int c = (l & 7) ^ (l >> 3);            // pre-swizzled source chunk
        const unsigned short* gp = src + (size_t)(r0 + r) * ld + k0 + c * 8;
        GLOAD16(gp, lds + chunk * 512);        // wave-uniform LDS base
    }
}

// ---------------- MFMA NT GEMM: C[M,N] = A[M,K] * B[N,K]^T, templated epilogue ----------------
// EPI 0: Cf = acc + e0[col] (bias); optional Ch = bf16(Cf)
// EPI 1: Ch = bf16(exp(acc*SCALE - e0[row]))            (e0 = Mrow, batch-offset)
// EPI 2: Cf = acc + (e0[col] - e1[ib[row]*D_+col])/S_   (rowterm)
template<int EPI>
__global__ __launch_bounds__(256) void mfma_nt(
    const unsigned short* __restrict__ A, const unsigned short* __restrict__ B,
    int M, int N, int K, long long zA, long long zB,
    float* __restrict__ Cf, long long zC,
    unsigned short* __restrict__ Ch, long long zCh,
    const float* __restrict__ e0, long long z0,
    const float* __restrict__ e1, long long z1,
    const int* __restrict__ ib, long long zi)
{
    __shared__ unsigned short Als[128 * 64];
    __shared__ unsigned short Bls[128 * 64];
    int tid = threadIdx.x;
    int w = tid >> 6, l = tid & 63;
    int wr = w >> 1, wc = w & 1;
    int zb = blockIdx.z;
    A += zb * zA;  B += zb * zB;
    int m0 = blockIdx.y * 128, n0 = blockIdx.x * 128;

    f32x4 acc[4][4] = {};
    int rl = l & 15, hi = l >> 4;

    for (int k0 = 0; k0 < K; k0 += 64) {
        stage_tile(A, m0, k0, K, Als, w, l);
        stage_tile(B, n0, k0, K, Bls, w, l);
        __syncthreads();
        bf16v8 af[4][2], bfr[4][2];
        const char* Ab = (const char*)Als;
        const char* Bb = (const char*)Bls;
        #pragma unroll
        for (int f = 0; f < 4; ++f) {
            #pragma unroll
            for (int kk = 0; kk < 2; ++kk) {
                int kb = kk * 64 + hi * 16;
                int ra = wr * 64 + f * 16 + rl;
                af[f][kk] = *(const bf16v8*)(Ab + ra * 128 + (kb ^ ((ra & 7) << 4)));
                int rb = wc * 64 + f * 16 + rl;
                bfr[f][kk] = *(const bf16v8*)(Bb + rb * 128 + (kb ^ ((rb & 7) << 4)));
            }
        }
        #pragma unroll
        for (int fm = 0; fm < 4; ++fm)
            #pragma unroll
            for (int fn = 0; fn < 4; ++fn)
                #pragma unroll
                for (int kk = 0; kk < 2; ++kk)
                    acc[fm][fn] = __builtin_amdgcn_mfma_f32_16x16x32_bf16(
                        af[fm][kk], bfr[fn][kk], acc[fm][fn], 0, 0, 0);
        __syncthreads();
    }

    // epilogue
    if (EPI == 0) {
        #pragma unroll
        for (int fm = 0; fm < 4; ++fm)
            #pragma unroll
            for (int fn = 0; fn < 4; ++fn) {
                int col = n0 + wc * 64 + fn * 16 + rl;
                float bs = e0[col];
                #pragma unroll
                for (int r = 0; r < 4; ++r) {
                    int row = m0 + wr * 64 + fm * 16 + hi * 4 + r;
                    float cv = acc[fm][fn][r] + bs;
                    Cf[(size_t)row * N + col] = cv;
                    if (Ch) Ch[(size_t)row * N + col] = f2b(cv);
                }
            }
    } else if (EPI == 1) {
        Ch += zb * zCh;  e0 += zb * z0;
        #pragma unroll
        for (int fm = 0; fm < 4; ++fm)
            #pragma unroll
            for (int fn = 0; fn < 4; ++fn) {
                int col = n0 + wc * 64 + fn * 16 + rl;
                #pragma unroll
                for (int r = 0; r < 4; ++r) {
                    int row = m0 + wr * 64 + fm * 16 + hi * 4 + r;
                    float ev = __expf(fmaf(acc[fm][fn][r], SCALE, -e0[row]));
                    Ch[(size_t)row * N + col] = f2b(ev);
                }
            }
    } else {
        Cf += zb * zC;  e0 += zb * z0;  e1 += zb * z1;  ib += zb * zi;
        const float invS = 1.0f / (float)S_;
        #pragma unroll
        for (int fm = 0; fm < 4; ++fm)
            #pragma unroll
            for (int fn = 0; fn < 4; ++fn) {
                int col = n0 + wc * 64 + fn * 16 + rl;
                float sva = e0[col];
                #pragma unroll
                for (int r = 0; r < 4; ++r) {
                    int row = m0 + wr * 64 + fm * 16 + hi * 4 + r;
                    int bm = ib[row];
                    float cv = acc[fm][fn][r] + (sva - e1[(size_t)bm * D_ + col]) * invS;
                    Cf[(size_t)row * N + col] = cv;
                }
            }
    }
}

// ---------------- f32 -> bf16 convert ----------------
typedef unsigned short u16x4 __attribute__((ext_vector_type(4)));
__global__ void convert_bf16(const float* __restrict__ src, unsigned short* __restrict__ dst, int n)
{
    for (int i = (blockIdx.x * 256 + threadIdx.x) * 4; i < n; i += gridDim.x * 1024) {
        float4 f = *(const float4*)(src + i);
        u16x4 u = { f2b(f.x), f2b(f.y), f2b(f.z), f2b(f.w) };
        *(u16x4*)(dst + i) = u;
    }
}

// ---------------- v f32 [b][S][D] -> vT bf16 [b][D][S] ----------------
__global__ __launch_bounds__(256) void transpose_v(
    const float* __restrict__ v, unsigned short* __restrict__ vT)
{
    __shared__ float tl[32][33];
    int b = blockIdx.z;
    int d0 = blockIdx.x * 32, s0 = blockIdx.y * 32;
    int tx = threadIdx.x & 31, ty = threadIdx.x >> 5;  // ty 0..7
    const float* vb = v + (size_t)b * S_ * D_;
    #pragma unroll
    for (int i = 0; i < 4; ++i)
        tl[ty + i * 8][tx] = vb[(size_t)(s0 + ty + i * 8) * D_ + d0 + tx];
    __syncthreads();
    unsigned short* vt = vT + (size_t)b * D_ * S_;
    #pragma unroll
    for (int i = 0; i < 4; ++i)
        vt[(size_t)(d0 + ty + i * 8) * S_ + s0 + tx] = f2b(tl[tx][ty + i * 8]);
}

// ---------------- buckets (f32 q) + M (from bf16-rounded q) ----------------
__global__ __launch_bounds__(64) void bucket_kernel(
    const float* __restrict__ q, const float* __restrict__ H,
    int* __restrict__ bucket, float* __restrict__ Mrow)
{
    int row = blockIdx.x;
    int lane = threadIdx.x;
    const float* qr = q + (size_t)row * D_;
    float proj[NH_] = {};
    float nrm = 0.f;
    for (int d = lane; d < D_; d += 64) {
        float qv = qr[d];
        float qb = b2f(f2b(qv));               // exactly the MFMA input value
        nrm = fmaf(qb, qb, nrm);
        #pragma unroll
        for (int n = 0; n < NH_; ++n)
            proj[n] = fmaf(qv, H[d * NH_ + n], proj[n]);
    }
    #pragma unroll
    for (int off = 32; off; off >>= 1) {
        nrm += __shfl_down(nrm, off);
        #pragma unroll
        for (int n = 0; n < NH_; ++n) proj[n] += __shfl_down(proj[n], off);
    }
    if (lane == 0) {
        int bk = 0;
        #pragma unroll
        for (int n = 0; n < NH_; ++n) {
            float p = proj[n] + H[D_ * NH_ + n];
            if (p >= 0.f) bk |= (1 << n);
        }
        bucket[row] = bk;
        Mrow[row] = nrm * SCALE;
    }
}

__global__ void zero_cnt(int* __restrict__ cnt) { cnt[threadIdx.x] = 0; }

__global__ __launch_bounds__(256) void hist_kernel(
    const int* __restrict__ bucket, int* __restrict__ cnt, int* __restrict__ idxl)
{
    int r = blockIdx.x * 256 + threadIdx.x;
    int b = r / S_;
    int s = r - b * S_;
    int j = bucket[r];
    int pos = atomicAdd(&cnt[b * NB_ + j], 1);
    idxl[((size_t)(b * NB_ + j)) * S_ + pos] = s;
}

__global__ __launch_bounds__(256) void sumv2_kernel(
    const float* __restrict__ v, const int* __restrict__ cnt,
    const int* __restrict__ idxl, float* __restrict__ sumVb)
{
    int j = blockIdx.x, b = blockIdx.y;
    int d = blockIdx.z * 256 + threadIdx.x;
    int n = cnt[b * NB_ + j];
    const int* lst = idxl + ((size_t)(b * NB_ + j)) * S_;
    const float* vb = v + (size_t)b * S_ * D_;
    float acc = 0.f;
    for (int k = 0; k < n; ++k)
        acc += vb[(size_t)lst[k] * D_ + d];
    sumVb[((size_t)b * NB_ + j) * D_ + d] = acc;
}

__global__ __launch_bounds__(256) void sumvall_kernel(
    const float* __restrict__ sumVb, float* __restrict__ sumVall)
{
    int b = blockIdx.y;
    int d = blockIdx.x * 256 + threadIdx.x;
    float acc = 0.f;
    for (int j = 0; j < NB_; ++j)
        acc += sumVb[((size_t)b * NB_ + j) * D_ + d];
    sumVall[b * D_ + d] = acc;
}

// ---------------- Z[row][j] = sum_{t in bucket j} Eh[row][t] ----------------
__global__ __launch_bounds__(256) void z_kernel(
    const unsigned short* __restrict__ Eh, const int* __restrict__ bucket,
    float* __restrict__ Z)
{
    int row = blockIdx.x;
    int b = row >> 11;
    __shared__ float zl[NB_];
    int tid = threadIdx.x;
    if (tid < NB_) zl[tid] = 0.f;
    __syncthreads();
    const unsigned short* Er = Eh + (size_t)row * S_;
    const int* bk = bucket + (size_t)b * S_;
    int t0 = tid * 8;
    s16x8 ev = *(const s16x8*)(Er + t0);
    int4 b0 = *(const int4*)(bk + t0);
    int4 b1 = *(const int4*)(bk + t0 + 4);
    atomicAdd(&zl[b0.x], b2f((unsigned short)ev[0]));
    atomicAdd(&zl[b0.y], b2f((unsigned short)ev[1]));
    atomicAdd(&zl[b0.z], b2f((unsigned short)ev[2]));
    atomicAdd(&zl[b0.w], b2f((unsigned short)ev[3]));
    atomicAdd(&zl[b1.x], b2f((unsigned short)ev[4]));
    atomicAdd(&zl[b1.y], b2f((unsigned short)ev[5]));
    atomicAdd(&zl[b1.z], b2f((unsigned short)ev[6]));
    atomicAdd(&zl[b1.w], b2f((unsigned short)ev[7]));
    __syncthreads();
    if (tid < NB_) Z[(size_t)row * NB_ + tid] = zl[tid];
}

__global__ __launch_bounds__(64) void w_kernel(
    const float* __restrict__ Z, const int* __restrict__ cnt,
    const int* __restrict__ bucket, const float* __restrict__ Mrow,
    float* __restrict__ wv, float* __restrict__ Wsum)
{
    int row = blockIdx.x;
    int j = threadIdx.x;
    int b = row >> 11;
    float zj = Z[(size_t)row * NB_ + j];
    float ztot = zj;
    #pragma unroll
    for (int off = 32; off; off >>= 1) ztot += __shfl_xor(ztot, off);
    int bs = bucket[row];
    float em = __expf(-Mrow[row]);
    float wj = 0.f;
    if (j != bs) wj = 1.0f / (ztot - zj + (float)cnt[b * NB_ + j] * em);
    float Wt = wj;
    #pragma unroll
    for (int off = 32; off; off >>= 1) Wt += __shfl_xor(Wt, off);
    wv[(size_t)row * NB_ + j] = wj;
    if (j == 0) Wsum[row] = Wt;
}

// ---------------- Eh *= (W[row] - w[row][bucket[t]])  (in-place bf16) ----------------
__global__ void gamma_kernel(
    unsigned short* __restrict__ Eh, const int* __restrict__ bucket,
    const float* __restrict__ wv, const float* __restrict__ Wsum)
{
    size_t total = (size_t)B_ * S_ * S_ / 8;
    for (size_t i = blockIdx.x * 256 + threadIdx.x; i < total; i += (size_t)gridDim.x * 256) {
        size_t row = i >> 8;                  // / (S_/8)
        int b = (int)(row >> 11);
        int t0 = ((int)i & 255) * 8;
        float Wt = Wsum[row];
        const float* wr = wv + row * NB_;
        const int* bk = bucket + (size_t)b * S_ + t0;
        int4 b0 = *(const int4*)bk;
        int4 b1 = *(const int4*)(bk + 4);
        unsigned short* ep = Eh + row * S_ + t0;
        s16x8 ev = *(const s16x8*)ep;
        s16x8 ov;
        ov[0] = (short)f2b(b2f((unsigned short)ev[0]) * (Wt - wr[b0.x]));
        ov[1] = (short)f2b(b2f((unsigned short)ev[1]) * (Wt - wr[b0.y]));
        ov[2] = (short)f2b(b2f((unsigned short)ev[2]) * (Wt - wr[b0.z]));
        ov[3] = (short)f2b(b2f((unsigned short)ev[3]) * (Wt - wr[b0.w]));
        ov[4] = (short)f2b(b2f((unsigned short)ev[4]) * (Wt - wr[b1.x]));
        ov[5] = (short)f2b(b2f((unsigned short)ev[5]) * (Wt - wr[b1.y]));
        ov[6] = (short)f2b(b2f((unsigned short)ev[6]) * (Wt - wr[b1.z]));
        ov[7] = (short)f2b(b2f((unsigned short)ev[7]) * (Wt - wr[b1.w]));
        *(s16x8*)ep = ov;
    }
}

extern "C" void kernel_launch(void* const* d_in, const int* in_sizes, int n_in,
                              void* d_out, int out_size, void* d_ws, size_t ws_size,
                              hipStream_t stream) {
    (void)in_sizes; (void)n_in; (void)out_size; (void)ws_size;
    const float* x  = (const float*)d_in[0];
    const float* Wq = (const float*)d_in[1];
    const float* bq = (const float*)d_in[2];
    const float* Wv = (const float*)d_in[3];
    const float* bv = (const float*)d_in[4];
    const float* H  = (const float*)d_in[5];
    float* out = (float*)d_out;

    char* p = (char*)d_ws;
    auto alloc = [&](size_t bytes) -> char* {
        char* r = p; p += (bytes + 255) & ~(size_t)255; return r;
    };
    float* q       = (float*)alloc((size_t)ROWS * D_ * 4);
    float* v       = (float*)alloc((size_t)ROWS * D_ * 4);
    float* Z       = (float*)alloc((size_t)ROWS * NB_ * 4);
    float* wbuf    = (float*)alloc((size_t)ROWS * NB_ * 4);
    float* Wsum    = (float*)alloc((size_t)ROWS * 4);
    float* Mrow    = (float*)alloc((size_t)ROWS * 4);
    float* sumVb   = (float*)alloc((size_t)B_ * NB_ * D_ * 4);
    float* sumVall = (float*)alloc((size_t)B_ * D_ * 4);
    int*   bucket  = (int*)alloc((size_t)ROWS * 4);
    int*   cnt     = (int*)alloc((size_t)B_ * NB_ * 4);
    int*   idxl    = (int*)alloc((size_t)B_ * NB_ * S_ * 4);
    unsigned short* xh  = (unsigned short*)alloc((size_t)ROWS * D_ * 2);
    unsigned short* qh  = (unsigned short*)alloc((size_t)ROWS * D_ * 2);
    unsigned short* Wqh = (unsigned short*)alloc((size_t)D_ * D_ * 2);
    unsigned short* Wvh = (unsigned short*)alloc((size_t)D_ * D_ * 2);
    unsigned short* vTh = (unsigned short*)alloc((size_t)B_ * D_ * S_ * 2);
    unsigned short* Eh  = (unsigned short*)alloc((size_t)B_ * S_ * S_ * 2);

    // 0. bf16 copies of x, Wq, Wv
    convert_bf16<<<2048, 256, 0, stream>>>(x, xh, ROWS * D_);
    convert_bf16<<<256, 256, 0, stream>>>(Wq, Wqh, D_ * D_);
    convert_bf16<<<256, 256, 0, stream>>>(Wv, Wvh, D_ * D_);
    // 1. q = x Wq^T + bq (f32 + bf16 copy); v = x Wv^T + bv (f32)
    mfma_nt<0><<<dim3(D_ / 128, ROWS / 128, 1), 256, 0, stream>>>(
        xh, Wqh, ROWS, D_, D_, 0, 0, q, 0, qh, 0, bq, 0, nullptr, 0, nullptr, 0);
    mfma_nt<0><<<dim3(D_ / 128, ROWS / 128, 1), 256, 0, stream>>>(
        xh, Wvh, ROWS, D_, D_, 0, 0, v, 0, nullptr, 0, bv, 0, nullptr, 0, nullptr, 0);
    // 2. buckets + M
    bucket_kernel<<<ROWS, 64, 0, stream>>>(q, H, bucket, Mrow);
    // 3. histogram + per-bucket sumV + total
    zero_cnt<<<1, B_ * NB_, 0, stream>>>(cnt);
    hist_kernel<<<ROWS / 256, 256, 0, stream>>>(bucket, cnt, idxl);
    sumv2_kernel<<<dim3(NB_, B_, D_ / 256), 256, 0, stream>>>(v, cnt, idxl, sumVb);
    sumvall_kernel<<<dim3(D_ / 256, B_), 256, 0, stream>>>(sumVb, sumVall);
    // 3b. vT bf16
    transpose_v<<<dim3(D_ / 32, S_ / 32, B_), 256, 0, stream>>>(v, vTh);
    // 4+5. Eh = bf16(exp(qh qh^T * scale - M)) per batch
    mfma_nt<1><<<dim3(S_ / 128, S_ / 128, B_), 256, 0, stream>>>(
        qh, qh, S_, S_, D_, (long long)S_ * D_, (long long)S_ * D_,
        nullptr, 0, Eh, (long long)S_ * S_, Mrow, S_, nullptr, 0, nullptr, 0);
    // 6. Z
    z_kernel<<<ROWS, 256, 0, stream>>>(Eh, bucket, Z);
    // 7. w, W
    w_kernel<<<ROWS, 64, 0, stream>>>(Z, cnt, bucket, Mrow, wbuf, Wsum);
    // 8. Eh *= Gamma (in place)
    gamma_kernel<<<2048, 256, 0, stream>>>(Eh, bucket, wbuf, Wsum);
    // 9. out = Eh' vT^T + rowterm
    mfma_nt<2><<<dim3(D_ / 128, S_ / 128, B_), 256, 0, stream>>>(
        Eh, vTh, S_, D_, S_, (long long)S_ * S_, (long long)D_ * S_,
        out, (long long)S_ * D_, nullptr, 0,
        sumVall, D_, sumVb, (long long)NB_ * D_, bucket, S_);
}

// Round 4
// 156.393 us; speedup vs baseline: 6.5607x; 1.2164x over previous
//
#include <hip/hip_runtime.h>
#include <math.h>

#define B_ 2
#define S_ 2048
#define D_ 512
#define NB_ 64
#define NH_ 6
#define ROWS (B_*S_)           // 4096
#define SCALE 0.044194173824159216f   // 1/sqrt(512)

typedef float f32x4 __attribute__((ext_vector_type(4)));
typedef __bf16 bf16v8 __attribute__((ext_vector_type(8)));
typedef short s16x8 __attribute__((ext_vector_type(8)));
typedef unsigned short u16x4 __attribute__((ext_vector_type(4)));

__device__ __forceinline__ float b2f(unsigned short u) {
    unsigned int v = (unsigned int)u << 16;
    float f; __builtin_memcpy(&f, &v, 4); return f;
}
__device__ __forceinline__ unsigned short f2b(float f) {
    unsigned int v; __builtin_memcpy(&v, &f, 4);
    v += 0x7fffu + ((v >> 16) & 1u);      // RNE
    return (unsigned short)(v >> 16);
}

#define GLOAD16(g, l) __builtin_amdgcn_global_load_lds( \
    (const __attribute__((address_space(1))) unsigned int*)(g), \
    (__attribute__((address_space(3))) unsigned int*)(uintptr_t)(l), 16, 0, 0)

// stage nch 1KB-chunks (8 rows x 64 bf16 each) with T2 content swizzle:
// LDS[r][g16] = G[r][g16 ^ (r&7)]  (inverse swizzle applied on global source)
__device__ __forceinline__ void stage_rows(
    const unsigned short* __restrict__ src, int r0, int k0, int ld,
    unsigned short* lds, int chunk0, int nch, int l)
{
    #pragma unroll
    for (int j = 0; j < nch; ++j) {
        int chunk = chunk0 + j;
        int r = chunk * 8 + (l >> 3);
        int c = (l & 7) ^ (l >> 3);
        GLOAD16(src + (size_t)(r0 + r) * ld + k0 + c * 8, lds + chunk * 512);
    }
}

// ---------------- MFMA NT GEMM, tile 128(M) x 64(N) x 64(K), 4 waves ----------------
// EPI 0 (fused proj, N=1024): col<512: q=acc+bq[col] (f32)+qh bf16 ; col>=512: v=acc+bv[col-512]
// EPI 1: Ch = bf16(exp(acc*SCALE - e0[row]))
// EPI 2: Cf = acc + (e0[col] - e1[ib[row]*D_+col])/S_
template<int EPI>
__global__ __launch_bounds__(256) void mfma_nt(
    const unsigned short* __restrict__ A, const unsigned short* __restrict__ B,
    int N, int K, long long zA, long long zB,
    float* __restrict__ Cf, long long zC,
    unsigned short* __restrict__ Ch, long long zCh,
    const float* __restrict__ e0, long long z0,
    const float* __restrict__ e1, long long z1,
    const int* __restrict__ ib, long long zi)
{
    __shared__ unsigned short Als[128 * 64];   // 16KB
    __shared__ unsigned short Bls[64 * 64];    // 8KB
    int tid = threadIdx.x;
    int w = tid >> 6, l = tid & 63;
    int wr = w >> 1, wc = w & 1;
    int zb = blockIdx.z;
    A += zb * zA;  B += zb * zB;

    // bijective XCD swizzle (nwg % 8 == 0 for all our grids)
    int gx = gridDim.x;
    int nwg = gx * gridDim.y;
    int lin = blockIdx.y * gx + blockIdx.x;
    int qq = nwg >> 3;
    int wg = (lin & 7) * qq + (lin >> 3);
    int m0 = (wg / gx) * 128, n0 = (wg % gx) * 64;

    f32x4 acc[4][2] = {};
    int rl = l & 15, hi = l >> 4;

    for (int k0 = 0; k0 < K; k0 += 64) {
        stage_rows(A, m0, k0, K, Als, w * 4, 4, l);
        stage_rows(B, n0, k0, K, Bls, w * 2, 2, l);
        __syncthreads();
        bf16v8 af[4][2], bfr[2][2];
        const char* Ab = (const char*)Als;
        const char* Bb = (const char*)Bls;
        #pragma unroll
        for (int kk = 0; kk < 2; ++kk) {
            int kb = kk * 64 + hi * 16;
            #pragma unroll
            for (int f = 0; f < 4; ++f) {
                int ra = wr * 64 + f * 16 + rl;
                af[f][kk] = *(const bf16v8*)(Ab + ra * 128 + (kb ^ ((ra & 7) << 4)));
            }
            #pragma unroll
            for (int f = 0; f < 2; ++f) {
                int rb = wc * 32 + f * 16 + rl;
                bfr[f][kk] = *(const bf16v8*)(Bb + rb * 128 + (kb ^ ((rb & 7) << 4)));
            }
        }
        #pragma unroll
        for (int fm = 0; fm < 4; ++fm)
            #pragma unroll
            for (int fn = 0; fn < 2; ++fn)
                #pragma unroll
                for (int kk = 0; kk < 2; ++kk)
                    acc[fm][fn] = __builtin_amdgcn_mfma_f32_16x16x32_bf16(
                        af[fm][kk], bfr[fn][kk], acc[fm][fn], 0, 0, 0);
        __syncthreads();
    }

    if (EPI == 0) {
        #pragma unroll
        for (int fm = 0; fm < 4; ++fm)
            #pragma unroll
            for (int fn = 0; fn < 2; ++fn) {
                int col = n0 + wc * 32 + fn * 16 + rl;
                if (col < D_) {
                    float bs = e0[col];
                    #pragma unroll
                    for (int r = 0; r < 4; ++r) {
                        int row = m0 + wr * 64 + fm * 16 + hi * 4 + r;
                        float cv = acc[fm][fn][r] + bs;
                        Cf[(size_t)row * D_ + col] = cv;         // q f32
                        Ch[(size_t)row * D_ + col] = f2b(cv);    // qh bf16
                    }
                } else {
                    int c2 = col - D_;
                    float bs = e1[c2];
                    #pragma unroll
                    for (int r = 0; r < 4; ++r) {
                        int row = m0 + wr * 64 + fm * 16 + hi * 4 + r;
                        float cv = acc[fm][fn][r] + bs;
                        ((float*)ib)[(size_t)row * D_ + c2] = cv; // v f32 (ib reused as v ptr)
                    }
                }
            }
    } else if (EPI == 1) {
        Ch += zb * zCh;  e0 += zb * z0;
        #pragma unroll
        for (int fm = 0; fm < 4; ++fm)
            #pragma unroll
            for (int fn = 0; fn < 2; ++fn) {
                int col = n0 + wc * 32 + fn * 16 + rl;
                #pragma unroll
                for (int r = 0; r < 4; ++r) {
                    int row = m0 + wr * 64 + fm * 16 + hi * 4 + r;
                    float ev = __expf(fmaf(acc[fm][fn][r], SCALE, -e0[row]));
                    Ch[(size_t)row * N + col] = f2b(ev);
                }
            }
    } else {
        Cf += zb * zC;  e0 += zb * z0;  e1 += zb * z1;  ib += zb * zi;
        const float invS = 1.0f / (float)S_;
        #pragma unroll
        for (int fm = 0; fm < 4; ++fm)
            #pragma unroll
            for (int fn = 0; fn < 2; ++fn) {
                int col = n0 + wc * 32 + fn * 16 + rl;
                float sva = e0[col];
                #pragma unroll
                for (int r = 0; r < 4; ++r) {
                    int row = m0 + wr * 64 + fm * 16 + hi * 4 + r;
                    int bm = ib[row];
                    Cf[(size_t)row * N + col] =
                        acc[fm][fn][r] + (sva - e1[(size_t)bm * D_ + col]) * invS;
                }
            }
    }
}

// ---------------- f32 -> bf16 convert ----------------
__global__ void convert_bf16(const float* __restrict__ src, unsigned short* __restrict__ dst, int n)
{
    for (int i = (blockIdx.x * 256 + threadIdx.x) * 4; i < n; i += gridDim.x * 1024) {
        float4 f = *(const float4*)(src + i);
        u16x4 u = { f2b(f.x), f2b(f.y), f2b(f.z), f2b(f.w) };
        *(u16x4*)(dst + i) = u;
    }
}

// ---------------- v f32 [b][S][D] -> vT bf16 [b][D][S] ----------------
__global__ __launch_bounds__(256) void transpose_v(
    const float* __restrict__ v, unsigned short* __restrict__ vT)
{
    __shared__ float tl[32][33];
    int b = blockIdx.z;
    int d0 = blockIdx.x * 32, s0 = blockIdx.y * 32;
    int tx = threadIdx.x & 31, ty = threadIdx.x >> 5;
    const float* vb = v + (size_t)b * S_ * D_;
    #pragma unroll
    for (int i = 0; i < 4; ++i)
        tl[ty + i * 8][tx] = vb[(size_t)(s0 + ty + i * 8) * D_ + d0 + tx];
    __syncthreads();
    unsigned short* vt = vT + (size_t)b * D_ * S_;
    #pragma unroll
    for (int i = 0; i < 4; ++i)
        vt[(size_t)(d0 + ty + i * 8) * S_ + s0 + tx] = f2b(tl[tx][ty + i * 8]);
}

// ---------------- buckets (f32 q) + M (from bf16-rounded q) ----------------
__global__ __launch_bounds__(64) void bucket_kernel(
    const float* __restrict__ q, const float* __restrict__ H,
    int* __restrict__ bucket, float* __restrict__ Mrow)
{
    int row = blockIdx.x;
    int lane = threadIdx.x;
    const float* qr = q + (size_t)row * D_;
    float proj[NH_] = {};
    float nrm = 0.f;
    for (int d = lane; d < D_; d += 64) {
        float qv = qr[d];
        float qb = b2f(f2b(qv));               // exactly the MFMA input value
        nrm = fmaf(qb, qb, nrm);
        #pragma unroll
        for (int n = 0; n < NH_; ++n)
            proj[n] = fmaf(qv, H[d * NH_ + n], proj[n]);
    }
    #pragma unroll
    for (int off = 32; off; off >>= 1) {
        nrm += __shfl_down(nrm, off);
        #pragma unroll
        for (int n = 0; n < NH_; ++n) proj[n] += __shfl_down(proj[n], off);
    }
    if (lane == 0) {
        int bk = 0;
        #pragma unroll
        for (int n = 0; n < NH_; ++n) {
            float p = proj[n] + H[D_ * NH_ + n];
            if (p >= 0.f) bk |= (1 << n);
        }
        bucket[row] = bk;
        Mrow[row] = nrm * SCALE;
    }
}

__global__ void zero_cnt(int* __restrict__ cnt) { cnt[threadIdx.x] = 0; }

__global__ __launch_bounds__(256) void hist_kernel(
    const int* __restrict__ bucket, int* __restrict__ cnt, int* __restrict__ idxl)
{
    int r = blockIdx.x * 256 + threadIdx.x;
    int b = r / S_;
    int s = r - b * S_;
    int j = bucket[r];
    int pos = atomicAdd(&cnt[b * NB_ + j], 1);
    idxl[((size_t)(b * NB_ + j)) * S_ + pos] = s;
}

__global__ __launch_bounds__(256) void sumv2_kernel(
    const float* __restrict__ v, const int* __restrict__ cnt,
    const int* __restrict__ idxl, float* __restrict__ sumVb)
{
    int j = blockIdx.x, b = blockIdx.y;
    int d = blockIdx.z * 256 + threadIdx.x;
    int n = cnt[b * NB_ + j];
    const int* lst = idxl + ((size_t)(b * NB_ + j)) * S_;
    const float* vb = v + (size_t)b * S_ * D_;
    float acc = 0.f;
    for (int k = 0; k < n; ++k)
        acc += vb[(size_t)lst[k] * D_ + d];
    sumVb[((size_t)b * NB_ + j) * D_ + d] = acc;
}

__global__ __launch_bounds__(256) void sumvall_kernel(
    const float* __restrict__ sumVb, float* __restrict__ sumVall)
{
    int b = blockIdx.y;
    int d = blockIdx.x * 256 + threadIdx.x;
    float acc = 0.f;
    for (int j = 0; j < NB_; ++j)
        acc += sumVb[((size_t)b * NB_ + j) * D_ + d];
    sumVall[b * D_ + d] = acc;
}

// ---------------- fused per-row: Z -> w -> Eh *= (W - w[bucket[t]]) ----------------
__global__ __launch_bounds__(256) void zwgamma_kernel(
    unsigned short* __restrict__ Eh, const int* __restrict__ bucket,
    const int* __restrict__ cnt, const float* __restrict__ Mrow)
{
    int row = blockIdx.x;            // 0..ROWS-1
    int b = row >> 11;
    __shared__ float zl[NB_];
    __shared__ float wl[NB_ + 1];
    int tid = threadIdx.x;
    if (tid < NB_) zl[tid] = 0.f;
    __syncthreads();
    unsigned short* Er = Eh + (size_t)row * S_;
    const int* bk = bucket + (size_t)b * S_;
    int t0 = tid * 8;
    s16x8 ev = *(const s16x8*)(Er + t0);
    int4 b0 = *(const int4*)(bk + t0);
    int4 b1 = *(const int4*)(bk + t0 + 4);
    float e0 = b2f((unsigned short)ev[0]), e1 = b2f((unsigned short)ev[1]);
    float e2 = b2f((unsigned short)ev[2]), e3 = b2f((unsigned short)ev[3]);
    float e4 = b2f((unsigned short)ev[4]), e5 = b2f((unsigned short)ev[5]);
    float e6 = b2f((unsigned short)ev[6]), e7 = b2f((unsigned short)ev[7]);
    atomicAdd(&zl[b0.x], e0); atomicAdd(&zl[b0.y], e1);
    atomicAdd(&zl[b0.z], e2); atomicAdd(&zl[b0.w], e3);
    atomicAdd(&zl[b1.x], e4); atomicAdd(&zl[b1.y], e5);
    atomicAdd(&zl[b1.z], e6); atomicAdd(&zl[b1.w], e7);
    __syncthreads();
    if (tid < 64) {
        int j = tid;
        float zj = zl[j];
        float ztot = zj;
        #pragma unroll
        for (int off = 32; off; off >>= 1) ztot += __shfl_xor(ztot, off);
        int bs = bucket[row];
        float em = __expf(-Mrow[row]);
        float wj = 0.f;
        if (j != bs) wj = 1.0f / (ztot - zj + (float)cnt[b * NB_ + j] * em);
        float Wt = wj;
        #pragma unroll
        for (int off = 32; off; off >>= 1) Wt += __shfl_xor(Wt, off);
        wl[j] = wj;
        if (j == 0) wl[NB_] = Wt;
    }
    __syncthreads();
    float Wt = wl[NB_];
    s16x8 ov;
    ov[0] = (short)f2b(e0 * (Wt - wl[b0.x]));
    ov[1] = (short)f2b(e1 * (Wt - wl[b0.y]));
    ov[2] = (short)f2b(e2 * (Wt - wl[b0.z]));
    ov[3] = (short)f2b(e3 * (Wt - wl[b0.w]));
    ov[4] = (short)f2b(e4 * (Wt - wl[b1.x]));
    ov[5] = (short)f2b(e5 * (Wt - wl[b1.y]));
    ov[6] = (short)f2b(e6 * (Wt - wl[b1.z]));
    ov[7] = (short)f2b(e7 * (Wt - wl[b1.w]));
    *(s16x8*)(Er + t0) = ov;
}

extern "C" void kernel_launch(void* const* d_in, const int* in_sizes, int n_in,
                              void* d_out, int out_size, void* d_ws, size_t ws_size,
                              hipStream_t stream) {
    (void)in_sizes; (void)n_in; (void)out_size; (void)ws_size;
    const float* x  = (const float*)d_in[0];
    const float* Wq = (const float*)d_in[1];
    const float* bq = (const float*)d_in[2];
    const float* Wv = (const float*)d_in[3];
    const float* bv = (const float*)d_in[4];
    const float* H  = (const float*)d_in[5];
    float* out = (float*)d_out;

    char* p = (char*)d_ws;
    auto alloc = [&](size_t bytes) -> char* {
        char* r = p; p += (bytes + 255) & ~(size_t)255; return r;
    };
    float* q       = (float*)alloc((size_t)ROWS * D_ * 4);
    float* v       = (float*)alloc((size_t)ROWS * D_ * 4);
    float* Mrow    = (float*)alloc((size_t)ROWS * 4);
    float* sumVb   = (float*)alloc((size_t)B_ * NB_ * D_ * 4);
    float* sumVall = (float*)alloc((size_t)B_ * D_ * 4);
    int*   bucket  = (int*)alloc((size_t)ROWS * 4);
    int*   cnt     = (int*)alloc((size_t)B_ * NB_ * 4);
    int*   idxl    = (int*)alloc((size_t)B_ * NB_ * S_ * 4);
    unsigned short* xh   = (unsigned short*)alloc((size_t)ROWS * D_ * 2);
    unsigned short* qh   = (unsigned short*)alloc((size_t)ROWS * D_ * 2);
    unsigned short* Wqvh = (unsigned short*)alloc((size_t)2 * D_ * D_ * 2); // Wq rows then Wv rows
    unsigned short* vTh  = (unsigned short*)alloc((size_t)B_ * D_ * S_ * 2);
    unsigned short* Eh   = (unsigned short*)alloc((size_t)B_ * S_ * S_ * 2);

    // 0. bf16 copies
    convert_bf16<<<2048, 256, 0, stream>>>(x, xh, ROWS * D_);
    convert_bf16<<<256, 256, 0, stream>>>(Wq, Wqvh, D_ * D_);
    convert_bf16<<<256, 256, 0, stream>>>(Wv, Wqvh + (size_t)D_ * D_, D_ * D_);
    // 1. fused q|v projection: N=1024
    mfma_nt<0><<<dim3(2 * D_ / 64, ROWS / 128, 1), 256, 0, stream>>>(
        xh, Wqvh, 2 * D_, D_, 0, 0, q, 0, qh, 0, bq, 0, bv, 0, (int*)v, 0);
    // 2. buckets + M
    bucket_kernel<<<ROWS, 64, 0, stream>>>(q, H, bucket, Mrow);
    // 3. histogram + per-bucket sumV + total
    zero_cnt<<<1, B_ * NB_, 0, stream>>>(cnt);
    hist_kernel<<<ROWS / 256, 256, 0, stream>>>(bucket, cnt, idxl);
    sumv2_kernel<<<dim3(NB_, B_, D_ / 256), 256, 0, stream>>>(v, cnt, idxl, sumVb);
    sumvall_kernel<<<dim3(D_ / 256, B_), 256, 0, stream>>>(sumVb, sumVall);
    // 3b. vT bf16
    transpose_v<<<dim3(D_ / 32, S_ / 32, B_), 256, 0, stream>>>(v, vTh);
    // 4+5. Eh = bf16(exp(qh qh^T * scale - M)) per batch
    mfma_nt<1><<<dim3(S_ / 64, S_ / 128, B_), 256, 0, stream>>>(
        qh, qh, S_, D_, (long long)S_ * D_, (long long)S_ * D_,
        nullptr, 0, Eh, (long long)S_ * S_, Mrow, S_, nullptr, 0, nullptr, 0);
    // 6+7+8. Z -> w -> gamma, fused per row, Eh in place
    zwgamma_kernel<<<ROWS, 256, 0, stream>>>(Eh, bucket, cnt, Mrow);
    // 9. out = Eh' vT^T + rowterm
    mfma_nt<2><<<dim3(D_ / 64, S_ / 128, B_), 256, 0, stream>>>(
        Eh, vTh, D_, S_, (long long)S_ * S_, (long long)D_ * S_,
        out, (long long)S_ * D_, nullptr, 0,
        sumVall, D_, sumVb, (long long)NB_ * D_, bucket, S_);
}

// Round 5
// 126.482 us; speedup vs baseline: 8.1122x; 1.2365x over previous
//
#include <hip/hip_runtime.h>
#include <math.h>

#define B_ 2
#define S_ 2048
#define D_ 512
#define NB_ 64
#define NH_ 6
#define ROWS (B_*S_)           // 4096
#define SCALE 0.044194173824159216f   // 1/sqrt(512)

typedef float f32x4 __attribute__((ext_vector_type(4)));
typedef __bf16 bf16v8 __attribute__((ext_vector_type(8)));
typedef short s16x8 __attribute__((ext_vector_type(8)));
typedef unsigned short u16x4 __attribute__((ext_vector_type(4)));

__device__ __forceinline__ float b2f(unsigned short u) {
    unsigned int v = (unsigned int)u << 16;
    float f; __builtin_memcpy(&f, &v, 4); return f;
}
__device__ __forceinline__ unsigned short f2b(float f) {
    unsigned int v; __builtin_memcpy(&v, &f, 4);
    v += 0x7fffu + ((v >> 16) & 1u);      // RNE
    return (unsigned short)(v >> 16);
}

#define GLOAD16(g, l) __builtin_amdgcn_global_load_lds( \
    (const __attribute__((address_space(1))) unsigned int*)(g), \
    (__attribute__((address_space(3))) unsigned int*)(uintptr_t)(l), 16, 0, 0)

// stage nch 1KB-chunks (8 rows x 64 bf16 each) with T2 content swizzle:
// LDS[r][g16] = G[r][g16 ^ (r&7)]  (inverse swizzle applied on global source)
__device__ __forceinline__ void stage_rows(
    const unsigned short* __restrict__ src, int r0, int k0, int ld,
    unsigned short* lds, int chunk0, int nch, int l)
{
    #pragma unroll
    for (int j = 0; j < nch; ++j) {
        int chunk = chunk0 + j;
        int r = chunk * 8 + (l >> 3);
        int c = (l & 7) ^ (l >> 3);
        GLOAD16(src + (size_t)(r0 + r) * ld + k0 + c * 8, lds + chunk * 512);
    }
}

// ---------------- MFMA NT GEMM, tile 128(M) x 64(N) x 64(K), 4 waves ----------------
// EPI 0 (fused proj, N=1024): col<512: q=acc+bq[col] (f32)+qh bf16 ; col>=512: v=acc+bv[col-512]
// EPI 1: Ch = bf16(exp(acc*SCALE - e0[row]))
// EPI 2: Cf = acc + (e0[col] - e1[ib[row]*D_+col])/S_
template<int EPI>
__global__ __launch_bounds__(256) void mfma_nt(
    const unsigned short* __restrict__ A, const unsigned short* __restrict__ B,
    int N, int K, long long zA, long long zB,
    float* __restrict__ Cf, long long zC,
    unsigned short* __restrict__ Ch, long long zCh,
    const float* __restrict__ e0, long long z0,
    const float* __restrict__ e1, long long z1,
    const int* __restrict__ ib, long long zi)
{
    __shared__ unsigned short Als[128 * 64];   // 16KB
    __shared__ unsigned short Bls[64 * 64];    // 8KB
    int tid = threadIdx.x;
    int w = tid >> 6, l = tid & 63;
    int wr = w >> 1, wc = w & 1;
    int zb = blockIdx.z;
    A += zb * zA;  B += zb * zB;

    // bijective XCD swizzle (nwg % 8 == 0 for all our grids)
    int gx = gridDim.x;
    int nwg = gx * gridDim.y;
    int lin = blockIdx.y * gx + blockIdx.x;
    int qq = nwg >> 3;
    int wg = (lin & 7) * qq + (lin >> 3);
    int m0 = (wg / gx) * 128, n0 = (wg % gx) * 64;

    f32x4 acc[4][2] = {};
    int rl = l & 15, hi = l >> 4;

    for (int k0 = 0; k0 < K; k0 += 64) {
        stage_rows(A, m0, k0, K, Als, w * 4, 4, l);
        stage_rows(B, n0, k0, K, Bls, w * 2, 2, l);
        __syncthreads();
        bf16v8 af[4][2], bfr[2][2];
        const char* Ab = (const char*)Als;
        const char* Bb = (const char*)Bls;
        #pragma unroll
        for (int kk = 0; kk < 2; ++kk) {
            int kb = kk * 64 + hi * 16;
            #pragma unroll
            for (int f = 0; f < 4; ++f) {
                int ra = wr * 64 + f * 16 + rl;
                af[f][kk] = *(const bf16v8*)(Ab + ra * 128 + (kb ^ ((ra & 7) << 4)));
            }
            #pragma unroll
            for (int f = 0; f < 2; ++f) {
                int rb = wc * 32 + f * 16 + rl;
                bfr[f][kk] = *(const bf16v8*)(Bb + rb * 128 + (kb ^ ((rb & 7) << 4)));
            }
        }
        #pragma unroll
        for (int fm = 0; fm < 4; ++fm)
            #pragma unroll
            for (int fn = 0; fn < 2; ++fn)
                #pragma unroll
                for (int kk = 0; kk < 2; ++kk)
                    acc[fm][fn] = __builtin_amdgcn_mfma_f32_16x16x32_bf16(
                        af[fm][kk], bfr[fn][kk], acc[fm][fn], 0, 0, 0);
        __syncthreads();
    }

    if (EPI == 0) {
        #pragma unroll
        for (int fm = 0; fm < 4; ++fm)
            #pragma unroll
            for (int fn = 0; fn < 2; ++fn) {
                int col = n0 + wc * 32 + fn * 16 + rl;
                if (col < D_) {
                    float bs = e0[col];
                    #pragma unroll
                    for (int r = 0; r < 4; ++r) {
                        int row = m0 + wr * 64 + fm * 16 + hi * 4 + r;
                        float cv = acc[fm][fn][r] + bs;
                        Cf[(size_t)row * D_ + col] = cv;         // q f32
                        Ch[(size_t)row * D_ + col] = f2b(cv);    // qh bf16
                    }
                } else {
                    int c2 = col - D_;
                    float bs = e1[c2];
                    #pragma unroll
                    for (int r = 0; r < 4; ++r) {
                        int row = m0 + wr * 64 + fm * 16 + hi * 4 + r;
                        float cv = acc[fm][fn][r] + bs;
                        ((float*)ib)[(size_t)row * D_ + c2] = cv; // v f32 (ib reused as v ptr)
                    }
                }
            }
    } else if (EPI == 1) {
        Ch += zb * zCh;  e0 += zb * z0;
        #pragma unroll
        for (int fm = 0; fm < 4; ++fm)
            #pragma unroll
            for (int fn = 0; fn < 2; ++fn) {
                int col = n0 + wc * 32 + fn * 16 + rl;
                #pragma unroll
                for (int r = 0; r < 4; ++r) {
                    int row = m0 + wr * 64 + fm * 16 + hi * 4 + r;
                    float ev = __expf(fmaf(acc[fm][fn][r], SCALE, -e0[row]));
                    Ch[(size_t)row * N + col] = f2b(ev);
                }
            }
    } else {
        Cf += zb * zC;  e0 += zb * z0;  e1 += zb * z1;  ib += zb * zi;
        const float invS = 1.0f / (float)S_;
        #pragma unroll
        for (int fm = 0; fm < 4; ++fm)
            #pragma unroll
            for (int fn = 0; fn < 2; ++fn) {
                int col = n0 + wc * 32 + fn * 16 + rl;
                float sva = e0[col];
                #pragma unroll
                for (int r = 0; r < 4; ++r) {
                    int row = m0 + wr * 64 + fm * 16 + hi * 4 + r;
                    int bm = ib[row];
                    Cf[(size_t)row * N + col] =
                        acc[fm][fn][r] + (sva - e1[(size_t)bm * D_ + col]) * invS;
                }
            }
    }
}

// ---------------- f32 -> bf16 convert ----------------
__global__ void convert_bf16(const float* __restrict__ src, unsigned short* __restrict__ dst, int n)
{
    for (int i = (blockIdx.x * 256 + threadIdx.x) * 4; i < n; i += gridDim.x * 1024) {
        float4 f = *(const float4*)(src + i);
        u16x4 u = { f2b(f.x), f2b(f.y), f2b(f.z), f2b(f.w) };
        *(u16x4*)(dst + i) = u;
    }
}

// ---------------- v f32 [b][S][D] -> vT bf16 [b][D][S'] with permuted S ----------------
__global__ __launch_bounds__(256) void transpose_v(
    const float* __restrict__ v, const int* __restrict__ perm,
    unsigned short* __restrict__ vT)
{
    __shared__ float tl[32][33];
    int b = blockIdx.z;
    int d0 = blockIdx.x * 32, s0 = blockIdx.y * 32;
    int tx = threadIdx.x & 31, ty = threadIdx.x >> 5;
    const float* vb = v + (size_t)b * S_ * D_;
    const int* pm = perm + (size_t)b * S_;
    #pragma unroll
    for (int i = 0; i < 4; ++i)
        tl[ty + i * 8][tx] = vb[(size_t)pm[s0 + ty + i * 8] * D_ + d0 + tx];
    __syncthreads();
    unsigned short* vt = vT + (size_t)b * D_ * S_;
    #pragma unroll
    for (int i = 0; i < 4; ++i)
        vt[(size_t)(d0 + ty + i * 8) * S_ + s0 + tx] = f2b(tl[tx][ty + i * 8]);
}

// ---------------- buckets (f32 q) + M (from bf16-rounded q) ----------------
__global__ __launch_bounds__(64) void bucket_kernel(
    const float* __restrict__ q, const float* __restrict__ H,
    int* __restrict__ bucket, float* __restrict__ Mrow)
{
    int row = blockIdx.x;
    int lane = threadIdx.x;
    const float* qr = q + (size_t)row * D_;
    float proj[NH_] = {};
    float nrm = 0.f;
    for (int d = lane; d < D_; d += 64) {
        float qv = qr[d];
        float qb = b2f(f2b(qv));               // exactly the MFMA input value
        nrm = fmaf(qb, qb, nrm);
        #pragma unroll
        for (int n = 0; n < NH_; ++n)
            proj[n] = fmaf(qv, H[d * NH_ + n], proj[n]);
    }
    #pragma unroll
    for (int off = 32; off; off >>= 1) {
        nrm += __shfl_down(nrm, off);
        #pragma unroll
        for (int n = 0; n < NH_; ++n) proj[n] += __shfl_down(proj[n], off);
    }
    if (lane == 0) {
        int bk = 0;
        #pragma unroll
        for (int n = 0; n < NH_; ++n) {
            float p = proj[n] + H[D_ * NH_ + n];
            if (p >= 0.f) bk |= (1 << n);
        }
        bucket[row] = bk;
        Mrow[row] = nrm * SCALE;
    }
}

__global__ void zero_cnt(int* __restrict__ cnt) { cnt[threadIdx.x] = 0; }

__global__ __launch_bounds__(256) void hist_kernel(
    const int* __restrict__ bucket, int* __restrict__ cnt, int* __restrict__ idxl)
{
    int r = blockIdx.x * 256 + threadIdx.x;
    int b = r / S_;
    int s = r - b * S_;
    int j = bucket[r];
    int pos = atomicAdd(&cnt[b * NB_ + j], 1);
    idxl[((size_t)(b * NB_ + j)) * S_ + pos] = s;
}

// ---------------- exclusive prefix sum of cnt -> off[b][0..64] ----------------
__global__ __launch_bounds__(64) void prefix_kernel(
    const int* __restrict__ cnt, int* __restrict__ off)
{
    int b = blockIdx.x;
    int j = threadIdx.x;
    int c = cnt[b * NB_ + j];
    int x = c;
    #pragma unroll
    for (int o = 1; o < 64; o <<= 1) {
        int y = __shfl_up(x, o);
        if (j >= o) x += y;
    }
    off[b * (NB_ + 1) + j] = x - c;
    if (j == 63) off[b * (NB_ + 1) + 64] = x;   // == S_
}

// ---------------- flatten idxl -> perm, p2b ----------------
__global__ __launch_bounds__(64) void permbuild_kernel(
    const int* __restrict__ idxl, const int* __restrict__ cnt,
    const int* __restrict__ off, int* __restrict__ perm, int* __restrict__ p2b)
{
    int j = blockIdx.x, b = blockIdx.y;
    int n = cnt[b * NB_ + j];
    int o = off[b * (NB_ + 1) + j];
    const int* lst = idxl + ((size_t)(b * NB_ + j)) * S_;
    for (int k = threadIdx.x; k < n; k += 64) {
        perm[(size_t)b * S_ + o + k] = lst[k];
        p2b[(size_t)b * S_ + o + k] = j;
    }
}

// ---------------- gather qh rows into permuted order ----------------
__global__ __launch_bounds__(64) void gatherq_kernel(
    const unsigned short* __restrict__ qh, const int* __restrict__ perm,
    unsigned short* __restrict__ qp)
{
    int tp = blockIdx.x;           // 0..ROWS-1 (permuted global row)
    int b = tp >> 11, tl = tp & (S_ - 1);
    int src = perm[(size_t)b * S_ + tl];
    const unsigned short* sp = qh + ((size_t)b * S_ + src) * D_;
    unsigned short* dp = qp + (size_t)tp * D_;
    int t = threadIdx.x * 8;
    *(s16x8*)(dp + t) = *(const s16x8*)(sp + t);
}

// ---------------- fused per-row: Z (segment sums) -> w -> Eh *= (W - w[p2b[t]]) ----------------
__global__ __launch_bounds__(256) void zwgamma_kernel(
    unsigned short* __restrict__ Eh, const int* __restrict__ p2b,
    const int* __restrict__ off, const int* __restrict__ cnt,
    const int* __restrict__ bucket, const float* __restrict__ Mrow)
{
    int row = blockIdx.x;            // 0..ROWS-1
    int b = row >> 11;
    __shared__ float er[S_];         // 8KB: row of E as f32
    __shared__ float zl[NB_];
    __shared__ float wl[NB_ + 1];
    int tid = threadIdx.x;
    unsigned short* Er = Eh + (size_t)row * S_;
    int t0 = tid * 8;
    s16x8 ev = *(const s16x8*)(Er + t0);
    #pragma unroll
    for (int i = 0; i < 8; ++i)
        er[t0 + i] = b2f((unsigned short)ev[i]);
    __syncthreads();
    // segment sums: 4 threads per bucket
    {
        int j = tid >> 2, sub = tid & 3;
        int lo = off[b * (NB_ + 1) + j], hiX = off[b * (NB_ + 1) + j + 1];
        float z = 0.f;
        for (int k = lo + sub; k < hiX; k += 4) z += er[k];
        z += __shfl_xor(z, 1);
        z += __shfl_xor(z, 2);
        if (sub == 0) zl[j] = z;
    }
    __syncthreads();
    if (tid < NB_) {
        int j = tid;
        float zj = zl[j];
        float ztot = zj;
        #pragma unroll
        for (int o = 32; o; o >>= 1) ztot += __shfl_xor(ztot, o);
        int bs = bucket[row];
        float em = __expf(-Mrow[row]);
        float wj = 0.f;
        if (j != bs) wj = 1.0f / (ztot - zj + (float)cnt[b * NB_ + j] * em);
        float Wt = wj;
        #pragma unroll
        for (int o = 32; o; o >>= 1) Wt += __shfl_xor(Wt, o);
        wl[j] = wj;
        if (j == 0) wl[NB_] = Wt;
    }
    __syncthreads();
    float Wt = wl[NB_];
    const int* pb = p2b + (size_t)b * S_ + t0;
    int4 b0 = *(const int4*)pb;
    int4 b1 = *(const int4*)(pb + 4);
    s16x8 ov;
    ov[0] = (short)f2b(er[t0 + 0] * (Wt - wl[b0.x]));
    ov[1] = (short)f2b(er[t0 + 1] * (Wt - wl[b0.y]));
    ov[2] = (short)f2b(er[t0 + 2] * (Wt - wl[b0.z]));
    ov[3] = (short)f2b(er[t0 + 3] * (Wt - wl[b0.w]));
    ov[4] = (short)f2b(er[t0 + 4] * (Wt - wl[b1.x]));
    ov[5] = (short)f2b(er[t0 + 5] * (Wt - wl[b1.y]));
    ov[6] = (short)f2b(er[t0 + 6] * (Wt - wl[b1.z]));
    ov[7] = (short)f2b(er[t0 + 7] * (Wt - wl[b1.w]));
    *(s16x8*)(Er + t0) = ov;
}

// ---------------- sumVb via idxl (unchanged) ----------------
__global__ __launch_bounds__(256) void sumv2_kernel(
    const float* __restrict__ v, const int* __restrict__ cnt,
    const int* __restrict__ idxl, float* __restrict__ sumVb)
{
    int j = blockIdx.x, b = blockIdx.y;
    int d = blockIdx.z * 256 + threadIdx.x;
    int n = cnt[b * NB_ + j];
    const int* lst = idxl + ((size_t)(b * NB_ + j)) * S_;
    const float* vb = v + (size_t)b * S_ * D_;
    float acc = 0.f;
    for (int k = 0; k < n; ++k)
        acc += vb[(size_t)lst[k] * D_ + d];
    sumVb[((size_t)b * NB_ + j) * D_ + d] = acc;
}

__global__ __launch_bounds__(256) void sumvall_kernel(
    const float* __restrict__ sumVb, float* __restrict__ sumVall)
{
    int b = blockIdx.y;
    int d = blockIdx.x * 256 + threadIdx.x;
    float acc = 0.f;
    for (int j = 0; j < NB_; ++j)
        acc += sumVb[((size_t)b * NB_ + j) * D_ + d];
    sumVall[b * D_ + d] = acc;
}

extern "C" void kernel_launch(void* const* d_in, const int* in_sizes, int n_in,
                              void* d_out, int out_size, void* d_ws, size_t ws_size,
                              hipStream_t stream) {
    (void)in_sizes; (void)n_in; (void)out_size; (void)ws_size;
    const float* x  = (const float*)d_in[0];
    const float* Wq = (const float*)d_in[1];
    const float* bq = (const float*)d_in[2];
    const float* Wv = (const float*)d_in[3];
    const float* bv = (const float*)d_in[4];
    const float* H  = (const float*)d_in[5];
    float* out = (float*)d_out;

    char* p = (char*)d_ws;
    auto alloc = [&](size_t bytes) -> char* {
        char* r = p; p += (bytes + 255) & ~(size_t)255; return r;
    };
    float* q       = (float*)alloc((size_t)ROWS * D_ * 4);
    float* v       = (float*)alloc((size_t)ROWS * D_ * 4);
    float* Mrow    = (float*)alloc((size_t)ROWS * 4);
    float* sumVb   = (float*)alloc((size_t)B_ * NB_ * D_ * 4);
    float* sumVall = (float*)alloc((size_t)B_ * D_ * 4);
    int*   bucket  = (int*)alloc((size_t)ROWS * 4);
    int*   cnt     = (int*)alloc((size_t)B_ * NB_ * 4);
    int*   offb    = (int*)alloc((size_t)B_ * (NB_ + 1) * 4);
    int*   perm    = (int*)alloc((size_t)B_ * S_ * 4);
    int*   p2b     = (int*)alloc((size_t)B_ * S_ * 4);
    int*   idxl    = (int*)alloc((size_t)B_ * NB_ * S_ * 4);
    unsigned short* xh   = (unsigned short*)alloc((size_t)ROWS * D_ * 2);
    unsigned short* qh   = (unsigned short*)alloc((size_t)ROWS * D_ * 2);
    unsigned short* qp   = (unsigned short*)alloc((size_t)ROWS * D_ * 2);
    unsigned short* Wqvh = (unsigned short*)alloc((size_t)2 * D_ * D_ * 2);
    unsigned short* vTh  = (unsigned short*)alloc((size_t)B_ * D_ * S_ * 2);
    unsigned short* Eh   = (unsigned short*)alloc((size_t)B_ * S_ * S_ * 2);

    // 0. bf16 copies
    convert_bf16<<<2048, 256, 0, stream>>>(x, xh, ROWS * D_);
    convert_bf16<<<256, 256, 0, stream>>>(Wq, Wqvh, D_ * D_);
    convert_bf16<<<256, 256, 0, stream>>>(Wv, Wqvh + (size_t)D_ * D_, D_ * D_);
    // 1. fused q|v projection: N=1024
    mfma_nt<0><<<dim3(2 * D_ / 64, ROWS / 128, 1), 256, 0, stream>>>(
        xh, Wqvh, 2 * D_, D_, 0, 0, q, 0, qh, 0, bq, 0, bv, 0, (int*)v, 0);
    // 2. buckets + M
    bucket_kernel<<<ROWS, 64, 0, stream>>>(q, H, bucket, Mrow);
    // 3. histogram -> prefix -> perm/p2b ; per-bucket sumV + total
    zero_cnt<<<1, B_ * NB_, 0, stream>>>(cnt);
    hist_kernel<<<ROWS / 256, 256, 0, stream>>>(bucket, cnt, idxl);
    prefix_kernel<<<B_, 64, 0, stream>>>(cnt, offb);
    permbuild_kernel<<<dim3(NB_, B_), 64, 0, stream>>>(idxl, cnt, offb, perm, p2b);
    gatherq_kernel<<<ROWS, 64, 0, stream>>>(qh, perm, qp);
    sumv2_kernel<<<dim3(NB_, B_, D_ / 256), 256, 0, stream>>>(v, cnt, idxl, sumVb);
    sumvall_kernel<<<dim3(D_ / 256, B_), 256, 0, stream>>>(sumVb, sumVall);
    // 3b. vT bf16, permuted token order
    transpose_v<<<dim3(D_ / 32, S_ / 32, B_), 256, 0, stream>>>(v, perm, vTh);
    // 4+5. Eh[row][t'] = bf16(exp(qh . qp[t'] * scale - M)) per batch (cols permuted)
    mfma_nt<1><<<dim3(S_ / 64, S_ / 128, B_), 256, 0, stream>>>(
        qh, qp, S_, D_, (long long)S_ * D_, (long long)S_ * D_,
        nullptr, 0, Eh, (long long)S_ * S_, Mrow, S_, nullptr, 0, nullptr, 0);
    // 6+7+8. Z (segment sums) -> w -> gamma, fused per row, Eh in place
    zwgamma_kernel<<<ROWS, 256, 0, stream>>>(Eh, p2b, offb, cnt, bucket, Mrow);
    // 9. out = Eh' vT^T + rowterm
    mfma_nt<2><<<dim3(D_ / 64, S_ / 128, B_), 256, 0, stream>>>(
        Eh, vTh, D_, S_, (long long)S_ * S_, (long long)D_ * S_,
        out, (long long)S_ * D_, nullptr, 0,
        sumVall, D_, sumVb, (long long)NB_ * D_, bucket, S_);
}